// Round 11
// baseline (205.488 us; speedup 1.0000x reference)
//
#include <hip/hip_runtime.h>

// AttentionBase: B=2, N=2048, D=1024, H=16, hd=64. fp32 in/out, bf16 MFMA inside.
#define D_MODEL 1024
#define N_TOK   2048
#define NHEAD   16
#define HDIM    64
#define BATCH   2
#define M_TOT   (BATCH*N_TOK)   // 4096 tokens

typedef unsigned short u16;
typedef __bf16 bf16x8 __attribute__((ext_vector_type(8)));
typedef float  f32x4  __attribute__((ext_vector_type(4)));

// attention scale folded into W_q: D^-0.5 * log2(e), so P = exp2(S) directly
#define QSCALE 0.04508422002777439f

__device__ __forceinline__ u16 f2bf(float f) {
  union { float f; unsigned u; } v; v.f = f;
  unsigned r = v.u + 0x7fffu + ((v.u >> 16) & 1u);   // RNE
  return (u16)(r >> 16);
}

__device__ __forceinline__ float bf2f(u16 u) {
  union { unsigned u; float f; } v; v.u = ((unsigned)u) << 16; return v.f;
}

__device__ __forceinline__ unsigned pk2bf(float a, float b) {
#if __has_builtin(__builtin_amdgcn_cvt_pk_bf16_f32)
  typedef __bf16 bf16x2_t __attribute__((ext_vector_type(2)));
  bf16x2_t r = __builtin_amdgcn_cvt_pk_bf16_f32(a, b);
  union { bf16x2_t v; unsigned u; } c; c.v = r; return c.u;
#else
  return (unsigned)f2bf(a) | ((unsigned)f2bf(b) << 16);
#endif
}

// (a_lo2 + b_lo2) * inv, packed bf16x2 word -> bf16x2 word
__device__ __forceinline__ unsigned comb2(unsigned a, unsigned b, float inv) {
  union { unsigned u; float f; } al, ah, bl, bh2;
  al.u = a << 16; ah.u = a & 0xffff0000u;
  bl.u = b << 16; bh2.u = b & 0xffff0000u;
  return pk2bf((al.f + bl.f) * inv, (ah.f + bh2.f) * inv);
}

__device__ __forceinline__ void gl2lds16(const void* g, void* l) {
  __builtin_amdgcn_global_load_lds(
      (__attribute__((address_space(1))) void*)g,
      (__attribute__((address_space(3))) void*)l, 16, 0, 0);
}

// ---------- fused prep: z<4 -> transpose+cast W[z]; z==4 -> cast x ----------
__global__ void prep_kernel(const float* __restrict__ x,
                            const float* __restrict__ s0, const float* __restrict__ s1,
                            const float* __restrict__ s2, const float* __restrict__ s3,
                            u16* __restrict__ xb,
                            u16* __restrict__ d0, u16* __restrict__ d1,
                            u16* __restrict__ d2, u16* __restrict__ d3) {
  const int t = threadIdx.y * 32 + threadIdx.x;
  if (blockIdx.z == 4) {
    // cast x: 1,048,576 float4 chunks; 1024 blocks x 256 thr x 4 iters
    int base = (blockIdx.y * 32 + blockIdx.x) * 256 + t;
#pragma unroll
    for (int r = 0; r < 4; ++r) {
      int i = base + r * 262144;
      float4 v = ((const float4*)x)[i];
      ushort4 o;
      o.x = f2bf(v.x); o.y = f2bf(v.y); o.z = f2bf(v.z); o.w = f2bf(v.w);
      ((ushort4*)xb)[i] = o;
    }
    return;
  }
  const float* src; u16* dst;
  switch (blockIdx.z) {
    case 0:  src = s0; dst = d0; break;
    case 1:  src = s1; dst = d1; break;
    case 2:  src = s2; dst = d2; break;
    default: src = s3; dst = d3; break;
  }
  float sc = (blockIdx.z == 0) ? QSCALE : 1.0f;
  __shared__ float tile[32][33];
  int xg = blockIdx.x * 32 + threadIdx.x;
  int ybase = blockIdx.y * 32;
#pragma unroll
  for (int r = 0; r < 4; ++r)
    tile[threadIdx.y + r*8][threadIdx.x] = src[(size_t)(ybase + threadIdx.y + r*8)*D_MODEL + xg];
  __syncthreads();
#pragma unroll
  for (int r = 0; r < 4; ++r)
    dst[(size_t)(blockIdx.x*32 + threadIdx.y + r*8)*D_MODEL + ybase + threadIdx.x] =
        f2bf(tile[threadIdx.x][threadIdx.y + r*8] * sc);
}

// ---------- 128x128 bf16 MFMA GEMM, double-buffered LDS, 1 barrier/k-iter ----
// Shared 32KB LDS passed from kernel (r13 lesson). m0/n0 passed (XCD swizzle).
// MODE 0: Q/K. Operand-SWAPPED mfma(bfr,af): acc regs run along d -> uint2.
// MODE 2: V^T [b,h,64,n] — original order, ushort4 along n.
template <int MODE>
__device__ __forceinline__ void gemm_body(const u16* __restrict__ A,
                                          const u16* __restrict__ Bt,
                                          void* __restrict__ Cout,
                                          u16* __restrict__ lA,
                                          u16* __restrict__ lB,
                                          int m0, int n0) {
  const int t = threadIdx.x;
  const int lane = t & 63, w = t >> 6;
  const int wm = w >> 1, wn = w & 1;
  const int q4 = lane >> 4, l15 = lane & 15;

  const int c0 = t, c1 = 256 + t;
  const int r0 = c0 >> 2, g0 = (c0 & 3) ^ (r0 & 3);
  const int r1 = c1 >> 2, g1 = (c1 & 3) ^ (r1 & 3);

  f32x4 acc[4][4] = {};

  gl2lds16(A  + (size_t)(m0 + r0)*D_MODEL + g0*8, lA + c0*8);
  gl2lds16(Bt + (size_t)(n0 + r0)*D_MODEL + g0*8, lB + c0*8);
  gl2lds16(A  + (size_t)(m0 + r1)*D_MODEL + g1*8, lA + c1*8);
  gl2lds16(Bt + (size_t)(n0 + r1)*D_MODEL + g1*8, lB + c1*8);

  for (int it = 0; it < 32; ++it) {
    const int cur = it & 1;
    __syncthreads();
    if (it + 1 < 32) {
      const int kn = (it + 1) * 32;
      u16* dA = lA + (cur ^ 1) * (128*32); u16* dB = lB + (cur ^ 1) * (128*32);
      gl2lds16(A  + (size_t)(m0 + r0)*D_MODEL + kn + g0*8, dA + c0*8);
      gl2lds16(Bt + (size_t)(n0 + r0)*D_MODEL + kn + g0*8, dB + c0*8);
      gl2lds16(A  + (size_t)(m0 + r1)*D_MODEL + kn + g1*8, dA + c1*8);
      gl2lds16(Bt + (size_t)(n0 + r1)*D_MODEL + kn + g1*8, dB + c1*8);
    }
    const u16* sA = lA + cur * (128*32); const u16* sB = lB + cur * (128*32);
    bf16x8 af[4], bfr[4];
#pragma unroll
    for (int mi = 0; mi < 4; ++mi) {
      int r = wm*64 + mi*16 + l15;
      af[mi] = *(const bf16x8*)(sA + r*32 + ((q4 ^ (r & 3)) * 8));
    }
#pragma unroll
    for (int ni = 0; ni < 4; ++ni) {
      int r = wn*64 + ni*16 + l15;
      bfr[ni] = *(const bf16x8*)(sB + r*32 + ((q4 ^ (r & 3)) * 8));
    }
#pragma unroll
    for (int mi = 0; mi < 4; ++mi)
#pragma unroll
      for (int ni = 0; ni < 4; ++ni) {
        if (MODE == 0)
          acc[mi][ni] = __builtin_amdgcn_mfma_f32_16x16x32_bf16(bfr[ni], af[mi], acc[mi][ni], 0, 0, 0);
        else
          acc[mi][ni] = __builtin_amdgcn_mfma_f32_16x16x32_bf16(af[mi], bfr[ni], acc[mi][ni], 0, 0, 0);
      }
  }

#pragma unroll
  for (int mi = 0; mi < 4; ++mi) {
#pragma unroll
    for (int ni = 0; ni < 4; ++ni) {
      if (MODE == 0) {
        // swapped: acc regs run along weight-col (d) dim
        const int tok = m0 + wm*64 + mi*16 + l15;
        const int col0 = n0 + wn*64 + ni*16 + q4*4;
        const int b = tok >> 11, n = tok & (N_TOK-1);
        const int h = col0 >> 6, d = col0 & (HDIM-1);
        uint2 u;
        u.x = pk2bf(acc[mi][ni][0], acc[mi][ni][1]);
        u.y = pk2bf(acc[mi][ni][2], acc[mi][ni][3]);
        *(uint2*)((u16*)Cout + (((size_t)(b*NHEAD + h))*N_TOK + n)*HDIM + d) = u;
      } else {
        const int tok0 = m0 + wm*64 + mi*16 + q4*4;
        const int col  = n0 + wn*64 + ni*16 + l15;
        int b = tok0 >> 11, n = tok0 & (N_TOK-1);
        int h = col >> 6, d = col & (HDIM-1);
        ushort4 pk;
        pk.x = f2bf(acc[mi][ni][0]); pk.y = f2bf(acc[mi][ni][1]);
        pk.z = f2bf(acc[mi][ni][2]); pk.w = f2bf(acc[mi][ni][3]);
        *(ushort4*)((u16*)Cout + ((size_t)(b*NHEAD + h)*HDIM + d)*N_TOK + n) = pk;
      }
    }
  }
}

// XCD partition (gx=2, gy=4): minimizes HBM dup 8*gx + 6*gy. XCD c (=bid%8)
// owns x in [cx*4, cx*4+4), y in [cy*8, cy*8+8), all z. A(xb) fetched 2x
// instead of 8x. Bijective: 8 XCD x 96 = 3*32*8.
__global__ __launch_bounds__(256) void qkv_kernel(const u16* __restrict__ xb,
    const u16* __restrict__ wqt, const u16* __restrict__ wkt, const u16* __restrict__ wvt,
    u16* __restrict__ Q, u16* __restrict__ K, u16* __restrict__ Vt) {
  __shared__ __attribute__((aligned(16))) u16 lA[2][128*32];
  __shared__ __attribute__((aligned(16))) u16 lB[2][128*32];
  const int bid = blockIdx.x + 8 * (blockIdx.y + 32 * blockIdx.z);
  const int c = bid & 7, i = bid >> 3;          // c: XCD, i: 0..95
  const int cx = c & 1, cy = c >> 1;
  const int xl = i & 3, rest = i >> 2;
  const int yl = rest & 7, zw = rest >> 3;      // zw: 0..2
  const int m0 = (cy * 8 + yl) * 128;
  const int n0 = (cx * 4 + xl) * 128;
  if (zw == 2) {
    gemm_body<2>(xb, wvt, (void*)Vt, &lA[0][0], &lB[0][0], m0, n0);
  } else {
    gemm_body<0>(xb, (zw == 0) ? wqt : wkt, (zw == 0) ? (void*)Q : (void*)K,
                 &lA[0][0], &lB[0][0], m0, n0);
  }
}

// ---------- out GEMM fused with combine: A = (O0+O1)*inv on the fly ---------
// 64x128 tile, dbuf, reg-staged A-combine, operand-swapped -> float4 stores.
// (r16's 32x128/4-blk-CU variant regressed: halving per-wave MFMA made iters
// staging-bound. 64x128 stands.) XCD (gx=1, gy=8): XCD c owns y = 8k+c.
__global__ __launch_bounds__(256) void out_kernel(const u16* __restrict__ Opart,
    const float* __restrict__ Lpart, const u16* __restrict__ wot,
    float* __restrict__ out) {
  __shared__ __attribute__((aligned(16))) u16 lA[2][64*32];
  __shared__ __attribute__((aligned(16))) u16 lB[2][128*32];
  const int t = threadIdx.x;
  const int lane = t & 63, w = t >> 6;
  const int wm = w >> 1, wn = w & 1;
  const int q4 = lane >> 4, l15 = lane & 15;
  const int bid = blockIdx.x + 8 * blockIdx.y;
  const int c = bid & 7, i = bid >> 3;          // i: 0..63
  const int m0 = ((i >> 3) * 8 + c) * 64;
  const int n0 = (i & 7) * 128;

  // A: 256 chunks (1/thread, reg-staged+combined); B: 512 chunks (2/thread)
  const int rA = t >> 2, gA = (t & 3) ^ (rA & 3);
  const int tokA = m0 + rA;
  const int bA = tokA >> 11, nA = tokA & (N_TOK-1);
  const int lbase = bA*NHEAD*N_TOK + nA;      // + head*N_TOK (+32*N_TOK for half1)
  const size_t oBase = (size_t)tokA*D_MODEL + gA*8;

  const int c0 = t, c1 = 256 + t;
  const int r0 = c0 >> 2, g0 = (c0 & 3) ^ (r0 & 3);
  const int r1 = c1 >> 2, g1 = (c1 & 3) ^ (r1 & 3);

  f32x4 acc[2][4] = {};

  // prologue: stage A(0) via reg-combine, B(0) via global_load_lds
  {
    uint4 o0 = *(const uint4*)(Opart + oBase);
    uint4 o1 = *(const uint4*)(Opart + (size_t)(M_TOT*D_MODEL) + oBase);
    float l0 = Lpart[lbase];                 // head(it=0) = 0
    float l1 = Lpart[32*N_TOK + lbase];
    float inv = 1.0f / (l0 + l1);
    uint4 res;
    res.x = comb2(o0.x, o1.x, inv); res.y = comb2(o0.y, o1.y, inv);
    res.z = comb2(o0.z, o1.z, inv); res.w = comb2(o0.w, o1.w, inv);
    *(uint4*)(&lA[0][t*8]) = res;
  }
  gl2lds16(wot + (size_t)(n0 + r0)*D_MODEL + g0*8, &lB[0][c0*8]);
  gl2lds16(wot + (size_t)(n0 + r1)*D_MODEL + g1*8, &lB[0][c1*8]);

  for (int it = 0; it < 32; ++it) {
    const int cur = it & 1;
    __syncthreads();
    uint4 o0, o1; float l0 = 0.f, l1 = 0.f;
    if (it + 1 < 32) {
      const int kn = (it + 1) * 32;
      o0 = *(const uint4*)(Opart + oBase + kn);
      o1 = *(const uint4*)(Opart + (size_t)(M_TOT*D_MODEL) + oBase + kn);
      const int head = (it + 1) >> 1;
      l0 = Lpart[head*N_TOK + lbase];
      l1 = Lpart[32*N_TOK + head*N_TOK + lbase];
      u16* dB = &lB[cur ^ 1][0];
      gl2lds16(wot + (size_t)(n0 + r0)*D_MODEL + kn + g0*8, dB + c0*8);
      gl2lds16(wot + (size_t)(n0 + r1)*D_MODEL + kn + g1*8, dB + c1*8);
    }
    const u16* sA = &lA[cur][0]; const u16* sB = &lB[cur][0];
    bf16x8 af[2], bfr[4];
#pragma unroll
    for (int mi = 0; mi < 2; ++mi) {
      int r = wm*32 + mi*16 + l15;
      af[mi] = *(const bf16x8*)(sA + r*32 + ((q4 ^ (r & 3)) * 8));
    }
#pragma unroll
    for (int ni = 0; ni < 4; ++ni) {
      int r = wn*64 + ni*16 + l15;
      bfr[ni] = *(const bf16x8*)(sB + r*32 + ((q4 ^ (r & 3)) * 8));
    }
#pragma unroll
    for (int mi = 0; mi < 2; ++mi)
#pragma unroll
      for (int ni = 0; ni < 4; ++ni)
        acc[mi][ni] = __builtin_amdgcn_mfma_f32_16x16x32_bf16(bfr[ni], af[mi], acc[mi][ni], 0, 0, 0);
    if (it + 1 < 32) {
      float inv = 1.0f / (l0 + l1);
      uint4 res;
      res.x = comb2(o0.x, o1.x, inv); res.y = comb2(o0.y, o1.y, inv);
      res.z = comb2(o0.z, o1.z, inv); res.w = comb2(o0.w, o1.w, inv);
      *(uint4*)(&lA[cur ^ 1][t*8]) = res;
    }
  }

  // swapped epilogue: acc regs run along output cols -> float4 stores
#pragma unroll
  for (int mi = 0; mi < 2; ++mi) {
#pragma unroll
    for (int ni = 0; ni < 4; ++ni) {
      const int tok  = m0 + wm*32 + mi*16 + l15;
      const int col0 = n0 + wn*64 + ni*16 + q4*4;
      *(f32x4*)(out + (size_t)tok*D_MODEL + col0) = acc[mi][ni];
    }
  }
}

// ---------- flash attention, S^T form, kv-split x2, double-buffered kv-64 ---
// r9 structure (best measured). P in registers (permlane16_swap), lsum via
// ones-MFMA, QK C-zero hoisted. XCD partition: XCD c owns bh = {c,c+8,c+16,
// c+24} -> K/V per XCD = 2MB, fully L2-resident. FETCH 41 -> 12.3MB.
__global__ __launch_bounds__(256, 4) void attn_kernel(const u16* __restrict__ Qg,
    const u16* __restrict__ Kg, const u16* __restrict__ Vtg,
    u16* __restrict__ Opart, float* __restrict__ Lpart) {
  __shared__ __attribute__((aligned(16))) u16 lds[16384];
  const int t = threadIdx.x;
  const int lane = t & 63, w = t >> 6;
  const int q4 = lane >> 4, l15 = lane & 15;
  const int q4sw = ((q4 & 1) << 1) | (q4 >> 1);   // k<->kv row permutation
  const int bid = blockIdx.x + 32 * blockIdx.y;
  const int c = bid & 7, i = bid >> 3;            // i: 0..127
  const int bh = (i & 3) * 8 + c;
  const int xw = i >> 2;                          // 0..31
  const int qb = xw >> 1, half = xw & 1;
  const int qw0 = qb * 128 + w * 32;
  const size_t kvBase = (size_t)bh * (N_TOK * HDIM);

  const int ck0 = t, ck1 = 256 + t;
  const int kr0 = ck0 >> 3, kg0 = (ck0 & 7) ^ (kr0 & 7);
  const int kr1 = ck1 >> 3, kg1 = (ck1 & 7) ^ (kr1 & 7);

  bf16x8 qf[2][2];
#pragma unroll
  for (int ni = 0; ni < 2; ++ni)
#pragma unroll
    for (int kk = 0; kk < 2; ++kk)
      qf[ni][kk] = *(const bf16x8*)(Qg + kvBase +
                    (size_t)(qw0 + ni*16 + l15)*HDIM + kk*32 + q4*8);

  f32x4 accO[4][2] = {};
  f32x4 accL[2] = {};                       // lsum accumulators (all-rows equal)
  const f32x4 fzero = {0.f, 0.f, 0.f, 0.f}; // hoisted zero C-operand for QK
  union { unsigned uu[4]; bf16x8 v; } onesU;
  onesU.uu[0] = 0x3F803F80u; onesU.uu[1] = 0x3F803F80u;
  onesU.uu[2] = 0x3F803F80u; onesU.uu[3] = 0x3F803F80u;
  const bf16x8 ones = onesU.v;              // bf16 1.0 x8

  const int kvStart = half * 1024;
  gl2lds16(Kg  + kvBase + (size_t)(kvStart + kr0)*HDIM + kg0*8, lds + ck0*8);
  gl2lds16(Kg  + kvBase + (size_t)(kvStart + kr1)*HDIM + kg1*8, lds + ck1*8);
  gl2lds16(Vtg + kvBase + (size_t)kr0*N_TOK + kvStart + kg0*8,  lds + 8192 + ck0*8);
  gl2lds16(Vtg + kvBase + (size_t)kr1*N_TOK + kvStart + kg1*8,  lds + 8192 + ck1*8);

  for (int it = 0; it < 16; ++it) {
    const int cur = it & 1;
    __syncthreads();
    if (it + 1 < 16) {
      const int kvn = kvStart + (it + 1) * 64;
      u16* dK = lds + (cur ^ 1) * 4096;
      u16* dV = lds + 8192 + (cur ^ 1) * 4096;
      gl2lds16(Kg  + kvBase + (size_t)(kvn + kr0)*HDIM + kg0*8, dK + ck0*8);
      gl2lds16(Kg  + kvBase + (size_t)(kvn + kr1)*HDIM + kg1*8, dK + ck1*8);
      gl2lds16(Vtg + kvBase + (size_t)kr0*N_TOK + kvn + kg0*8,  dV + ck0*8);
      gl2lds16(Vtg + kvBase + (size_t)kr1*N_TOK + kvn + kg1*8,  dV + ck1*8);
    }
    const u16* sK = lds + cur * 4096;
    const u16* sV = lds + 8192 + cur * 4096;

    // ---- QK^T + exp2, P packed to bf16 words in registers ----
    unsigned wv[4][2][2];   // [mip][ni][j] : all indices compile-time after unroll
#pragma unroll
    for (int mip = 0; mip < 4; ++mip) {
      const int kv = mip*16 + l15;
      __builtin_amdgcn_s_setprio(1);
      bf16x8 a0 = *(const bf16x8*)(sK + kv*64 + (((q4    ) ^ (l15 & 7)) * 8));
      bf16x8 a1 = *(const bf16x8*)(sK + kv*64 + (((4 + q4) ^ (l15 & 7)) * 8));
      f32x4 s0, s1;
      s0 = __builtin_amdgcn_mfma_f32_16x16x32_bf16(a0, qf[0][0], fzero, 0, 0, 0);
      s1 = __builtin_amdgcn_mfma_f32_16x16x32_bf16(a0, qf[1][0], fzero, 0, 0, 0);
      s0 = __builtin_amdgcn_mfma_f32_16x16x32_bf16(a1, qf[0][1], s0, 0, 0, 0);
      s1 = __builtin_amdgcn_mfma_f32_16x16x32_bf16(a1, qf[1][1], s1, 0, 0, 0);
      __builtin_amdgcn_s_setprio(0);
      wv[mip][0][0] = pk2bf(__builtin_amdgcn_exp2f(s0[0]), __builtin_amdgcn_exp2f(s0[1]));
      wv[mip][0][1] = pk2bf(__builtin_amdgcn_exp2f(s0[2]), __builtin_amdgcn_exp2f(s0[3]));
      wv[mip][1][0] = pk2bf(__builtin_amdgcn_exp2f(s1[0]), __builtin_amdgcn_exp2f(s1[1]));
      wv[mip][1][1] = pk2bf(__builtin_amdgcn_exp2f(s1[2]), __builtin_amdgcn_exp2f(s1[3]));
    }

    // ---- permlane16_swap: rows (q4 groups) -> PV B-fragments, no LDS ----
    // After swap(x=w(m0,j), y=w(m1,j)): x' = [x.r0, y.r0, x.r2, y.r2],
    //                                   y' = [x.r1, y.r1, x.r3, y.r3].
    // Lane row q4 then holds kv {0-7 | 16-23 | 8-15 | 24-31} (+32*kk2),
    // i.e. kv-group swap(q4) — matched by q4sw on the V read below.
    bf16x8 bp[2][2];
#pragma unroll
    for (int ni = 0; ni < 2; ++ni)
#pragma unroll
      for (int kk2 = 0; kk2 < 2; ++kk2) {
        unsigned x0 = wv[2*kk2][ni][0], x1 = wv[2*kk2][ni][1];
        unsigned y0 = wv[2*kk2+1][ni][0], y1 = wv[2*kk2+1][ni][1];
        asm("v_permlane16_swap_b32 %0, %1" : "+v"(x0), "+v"(y0));
        asm("v_permlane16_swap_b32 %0, %1" : "+v"(x1), "+v"(y1));
        union { unsigned u[4]; bf16x8 v; } pb;
        pb.u[0] = x0; pb.u[1] = x1; pb.u[2] = y0; pb.u[3] = y1;
        bp[ni][kk2] = pb.v;
      }

    // ---- PV (+ lsum via ones-MFMA) ----
    __builtin_amdgcn_s_setprio(1);
#pragma unroll
    for (int kk2 = 0; kk2 < 2; ++kk2) {
      accL[0] = __builtin_amdgcn_mfma_f32_16x16x32_bf16(ones, bp[0][kk2], accL[0], 0, 0, 0);
      accL[1] = __builtin_amdgcn_mfma_f32_16x16x32_bf16(ones, bp[1][kk2], accL[1], 0, 0, 0);
#pragma unroll
      for (int mi2 = 0; mi2 < 4; ++mi2) {
        const int d = mi2*16 + l15;
        bf16x8 av = *(const bf16x8*)(sV + d*64 + (((kk2*4 + q4sw) ^ (d & 7)) * 8));
#pragma unroll
        for (int ni = 0; ni < 2; ++ni)
          accO[mi2][ni] = __builtin_amdgcn_mfma_f32_16x16x32_bf16(av, bp[ni][kk2], accO[mi2][ni], 0, 0, 0);
      }
    }
    __builtin_amdgcn_s_setprio(0);
  }

  // epilogue: bf16 partial O^T (unnormalized) + fp32 partial row-sums.
  // accL[ni][r] holds sum_kv P[kv][q] for q=qw0+ni*16+l15 in EVERY lane/reg.
  const int b = bh >> 4, head = bh & (NHEAD-1);
  u16* Obase = Opart + (size_t)half * (M_TOT * D_MODEL);
#pragma unroll
  for (int ni = 0; ni < 2; ++ni) {
    const int q = qw0 + ni*16 + l15;
    if (q4 == 0)
      Lpart[(size_t)half*(32*N_TOK) + bh*N_TOK + q] = accL[ni][0];
    const size_t rb = ((size_t)(b*N_TOK + q))*D_MODEL + head*HDIM + q4*4;
#pragma unroll
    for (int mi2 = 0; mi2 < 4; ++mi2) {
      uint2 u;
      u.x = pk2bf(accO[mi2][ni][0], accO[mi2][ni][1]);
      u.y = pk2bf(accO[mi2][ni][2], accO[mi2][ni][3]);
      *(uint2*)(Obase + rb + mi2*16) = u;
    }
  }
}

extern "C" void kernel_launch(void* const* d_in, const int* in_sizes, int n_in,
                              void* d_out, int out_size, void* d_ws, size_t ws_size,
                              hipStream_t stream) {
  const float* x  = (const float*)d_in[0];
  const float* Wq = (const float*)d_in[1];
  const float* Wk = (const float*)d_in[2];
  const float* Wv = (const float*)d_in[3];
  const float* Wo = (const float*)d_in[4];
  float* out = (float*)d_out;

  char* ws = (char*)d_ws;
  u16* xb   = (u16*)(ws);                     // 8 MB  [4096][1024]
  u16* wqt  = (u16*)(ws + (8u  << 20));       // 2 MB each, transposed [out][k]
  u16* wkt  = (u16*)(ws + (10u << 20));
  u16* wvt  = (u16*)(ws + (12u << 20));
  u16* wot  = (u16*)(ws + (14u << 20));
  u16* Qw   = (u16*)(ws + (16u << 20));       // 8 MB  [bh][n][64]  (pre-scaled)
  u16* Kw   = (u16*)(ws + (24u << 20));       // 8 MB  [bh][n][64]
  u16* Vtw  = (u16*)(ws + (32u << 20));       // 8 MB  [bh][64][n]
  u16* Op   = (u16*)(ws + (48u << 20));       // 16 MB [2][4096][1024] bf16
  float* Lp = (float*)(ws + (64u << 20));     // 512KB [2][32][2048] fp32
  (void)in_sizes; (void)n_in; (void)out_size; (void)ws_size;

  prep_kernel<<<dim3(32, 32, 5), dim3(32, 8), 0, stream>>>(x, Wq, Wk, Wv, Wo,
                                                           xb, wqt, wkt, wvt, wot);
  qkv_kernel<<<dim3(8, 32, 3), 256, 0, stream>>>(xb, wqt, wkt, wvt, Qw, Kw, Vtw);
  attn_kernel<<<dim3(32, 32), 256, 0, stream>>>(Qw, Kw, Vtw, Op, Lp);
  out_kernel<<<dim3(8, 64), 256, 0, stream>>>(Op, Lp, wot, out);
}

// Round 12
// 194.840 us; speedup vs baseline: 1.0546x; 1.0546x over previous
//
#include <hip/hip_runtime.h>

// AttentionBase: B=2, N=2048, D=1024, H=16, hd=64. fp32 in/out, bf16 MFMA inside.
#define D_MODEL 1024
#define N_TOK   2048
#define NHEAD   16
#define HDIM    64
#define BATCH   2
#define M_TOT   (BATCH*N_TOK)   // 4096 tokens

typedef unsigned short u16;
typedef __bf16 bf16x8 __attribute__((ext_vector_type(8)));
typedef float  f32x4  __attribute__((ext_vector_type(4)));

// attention scale folded into W_q: D^-0.5 * log2(e), so P = exp2(S) directly
#define QSCALE 0.04508422002777439f

__device__ __forceinline__ u16 f2bf(float f) {
  union { float f; unsigned u; } v; v.f = f;
  unsigned r = v.u + 0x7fffu + ((v.u >> 16) & 1u);   // RNE
  return (u16)(r >> 16);
}

__device__ __forceinline__ float bf2f(u16 u) {
  union { unsigned u; float f; } v; v.u = ((unsigned)u) << 16; return v.f;
}

__device__ __forceinline__ unsigned pk2bf(float a, float b) {
#if __has_builtin(__builtin_amdgcn_cvt_pk_bf16_f32)
  typedef __bf16 bf16x2_t __attribute__((ext_vector_type(2)));
  bf16x2_t r = __builtin_amdgcn_cvt_pk_bf16_f32(a, b);
  union { bf16x2_t v; unsigned u; } c; c.v = r; return c.u;
#else
  return (unsigned)f2bf(a) | ((unsigned)f2bf(b) << 16);
#endif
}

// (a_lo2 + b_lo2) * inv, packed bf16x2 word -> bf16x2 word
__device__ __forceinline__ unsigned comb2(unsigned a, unsigned b, float inv) {
  union { unsigned u; float f; } al, ah, bl, bh2;
  al.u = a << 16; ah.u = a & 0xffff0000u;
  bl.u = b << 16; bh2.u = b & 0xffff0000u;
  return pk2bf((al.f + bl.f) * inv, (ah.f + bh2.f) * inv);
}

__device__ __forceinline__ void gl2lds16(const void* g, void* l) {
  __builtin_amdgcn_global_load_lds(
      (__attribute__((address_space(1))) void*)g,
      (__attribute__((address_space(3))) void*)l, 16, 0, 0);
}

// ---------- prep: transpose+cast the 4 weight matrices (x-cast fused into qkv)
__global__ void prep_kernel(const float* __restrict__ s0, const float* __restrict__ s1,
                            const float* __restrict__ s2, const float* __restrict__ s3,
                            u16* __restrict__ d0, u16* __restrict__ d1,
                            u16* __restrict__ d2, u16* __restrict__ d3) {
  const float* src; u16* dst;
  switch (blockIdx.z) {
    case 0:  src = s0; dst = d0; break;
    case 1:  src = s1; dst = d1; break;
    case 2:  src = s2; dst = d2; break;
    default: src = s3; dst = d3; break;
  }
  float sc = (blockIdx.z == 0) ? QSCALE : 1.0f;
  __shared__ float tile[32][33];
  int xg = blockIdx.x * 32 + threadIdx.x;
  int ybase = blockIdx.y * 32;
#pragma unroll
  for (int r = 0; r < 4; ++r)
    tile[threadIdx.y + r*8][threadIdx.x] = src[(size_t)(ybase + threadIdx.y + r*8)*D_MODEL + xg];
  __syncthreads();
#pragma unroll
  for (int r = 0; r < 4; ++r)
    dst[(size_t)(blockIdx.x*32 + threadIdx.y + r*8)*D_MODEL + ybase + threadIdx.x] =
        f2bf(tile[threadIdx.x][threadIdx.y + r*8] * sc);
}

// ---------- 128x128 bf16 MFMA GEMM, double-buffered LDS, 1 barrier/k-iter ----
// A is fp32 x, reg-staged with fused bf16 cast (T14 split: float4 loads issued
// at phase top, cvt_pk + ds_write_b128 after the MFMA block). B via gl2lds.
// Writes to lA[cur^1] are race-free: cur^1's readers all passed the top
// barrier of this iteration (same hazard pattern as the gl2lds dbuf).
// Shared 32KB LDS passed from kernel (r13 lesson). m0/n0 passed (XCD swizzle).
// MODE 0: Q/K. Operand-SWAPPED mfma(bfr,af): acc regs run along d -> uint2.
// MODE 2: V^T [b,h,64,n] — original order, ushort4 along n.
template <int MODE>
__device__ __forceinline__ void gemm_body(const float* __restrict__ X,
                                          const u16* __restrict__ Bt,
                                          void* __restrict__ Cout,
                                          u16* __restrict__ lA,
                                          u16* __restrict__ lB,
                                          int m0, int n0) {
  const int t = threadIdx.x;
  const int lane = t & 63, w = t >> 6;
  const int wm = w >> 1, wn = w & 1;
  const int q4 = lane >> 4, l15 = lane & 15;

  const int c0 = t, c1 = 256 + t;
  const int r0 = c0 >> 2, g0 = (c0 & 3) ^ (r0 & 3);
  const int r1 = c1 >> 2, g1 = (c1 & 3) ^ (r1 & 3);

  const float* __restrict__ xr0 = X + (size_t)(m0 + r0)*D_MODEL + g0*8;
  const float* __restrict__ xr1 = X + (size_t)(m0 + r1)*D_MODEL + g1*8;

  f32x4 acc[4][4] = {};

  // prologue: A(0) reg-staged cast, B(0) via gl2lds
  {
    float4 f00 = ((const float4*)xr0)[0], f01 = ((const float4*)xr0)[1];
    float4 f10 = ((const float4*)xr1)[0], f11 = ((const float4*)xr1)[1];
    uint4 w0, w1;
    w0.x = pk2bf(f00.x, f00.y); w0.y = pk2bf(f00.z, f00.w);
    w0.z = pk2bf(f01.x, f01.y); w0.w = pk2bf(f01.z, f01.w);
    w1.x = pk2bf(f10.x, f10.y); w1.y = pk2bf(f10.z, f10.w);
    w1.z = pk2bf(f11.x, f11.y); w1.w = pk2bf(f11.z, f11.w);
    *(uint4*)(lA + c0*8) = w0;
    *(uint4*)(lA + c1*8) = w1;
  }
  gl2lds16(Bt + (size_t)(n0 + r0)*D_MODEL + g0*8, lB + c0*8);
  gl2lds16(Bt + (size_t)(n0 + r1)*D_MODEL + g1*8, lB + c1*8);

  for (int it = 0; it < 32; ++it) {
    const int cur = it & 1;
    __syncthreads();
    float4 f00, f01, f10, f11;
    if (it + 1 < 32) {
      const int kn = (it + 1) * 32;
      f00 = ((const float4*)(xr0 + kn))[0]; f01 = ((const float4*)(xr0 + kn))[1];
      f10 = ((const float4*)(xr1 + kn))[0]; f11 = ((const float4*)(xr1 + kn))[1];
      u16* dB = lB + (cur ^ 1) * (128*32);
      gl2lds16(Bt + (size_t)(n0 + r0)*D_MODEL + kn + g0*8, dB + c0*8);
      gl2lds16(Bt + (size_t)(n0 + r1)*D_MODEL + kn + g1*8, dB + c1*8);
    }
    const u16* sA = lA + cur * (128*32); const u16* sB = lB + cur * (128*32);
    bf16x8 af[4], bfr[4];
#pragma unroll
    for (int mi = 0; mi < 4; ++mi) {
      int r = wm*64 + mi*16 + l15;
      af[mi] = *(const bf16x8*)(sA + r*32 + ((q4 ^ (r & 3)) * 8));
    }
#pragma unroll
    for (int ni = 0; ni < 4; ++ni) {
      int r = wn*64 + ni*16 + l15;
      bfr[ni] = *(const bf16x8*)(sB + r*32 + ((q4 ^ (r & 3)) * 8));
    }
#pragma unroll
    for (int mi = 0; mi < 4; ++mi)
#pragma unroll
      for (int ni = 0; ni < 4; ++ni) {
        if (MODE == 0)
          acc[mi][ni] = __builtin_amdgcn_mfma_f32_16x16x32_bf16(bfr[ni], af[mi], acc[mi][ni], 0, 0, 0);
        else
          acc[mi][ni] = __builtin_amdgcn_mfma_f32_16x16x32_bf16(af[mi], bfr[ni], acc[mi][ni], 0, 0, 0);
      }
    if (it + 1 < 32) {
      u16* dA = lA + (cur ^ 1) * (128*32);
      uint4 w0, w1;
      w0.x = pk2bf(f00.x, f00.y); w0.y = pk2bf(f00.z, f00.w);
      w0.z = pk2bf(f01.x, f01.y); w0.w = pk2bf(f01.z, f01.w);
      w1.x = pk2bf(f10.x, f10.y); w1.y = pk2bf(f10.z, f10.w);
      w1.z = pk2bf(f11.x, f11.y); w1.w = pk2bf(f11.z, f11.w);
      *(uint4*)(dA + c0*8) = w0;
      *(uint4*)(dA + c1*8) = w1;
    }
  }

#pragma unroll
  for (int mi = 0; mi < 4; ++mi) {
#pragma unroll
    for (int ni = 0; ni < 4; ++ni) {
      if (MODE == 0) {
        // swapped: acc regs run along weight-col (d) dim
        const int tok = m0 + wm*64 + mi*16 + l15;
        const int col0 = n0 + wn*64 + ni*16 + q4*4;
        const int b = tok >> 11, n = tok & (N_TOK-1);
        const int h = col0 >> 6, d = col0 & (HDIM-1);
        uint2 u;
        u.x = pk2bf(acc[mi][ni][0], acc[mi][ni][1]);
        u.y = pk2bf(acc[mi][ni][2], acc[mi][ni][3]);
        *(uint2*)((u16*)Cout + (((size_t)(b*NHEAD + h))*N_TOK + n)*HDIM + d) = u;
      } else {
        const int tok0 = m0 + wm*64 + mi*16 + q4*4;
        const int col  = n0 + wn*64 + ni*16 + l15;
        int b = tok0 >> 11, n = tok0 & (N_TOK-1);
        int h = col >> 6, d = col & (HDIM-1);
        ushort4 pk;
        pk.x = f2bf(acc[mi][ni][0]); pk.y = f2bf(acc[mi][ni][1]);
        pk.z = f2bf(acc[mi][ni][2]); pk.w = f2bf(acc[mi][ni][3]);
        *(ushort4*)((u16*)Cout + ((size_t)(b*NHEAD + h)*HDIM + d)*N_TOK + n) = pk;
      }
    }
  }
}

// XCD partition (gx=2, gy=4): XCD c (=bid%8) owns x in [cx*4, cx*4+4),
// y in [cy*8, cy*8+8), all z. Bijective: 8 XCD x 96 = 3*32*8.
__global__ __launch_bounds__(256) void qkv_kernel(const float* __restrict__ x,
    const u16* __restrict__ wqt, const u16* __restrict__ wkt, const u16* __restrict__ wvt,
    u16* __restrict__ Q, u16* __restrict__ K, u16* __restrict__ Vt) {
  __shared__ __attribute__((aligned(16))) u16 lA[2][128*32];
  __shared__ __attribute__((aligned(16))) u16 lB[2][128*32];
  const int bid = blockIdx.x + 8 * (blockIdx.y + 32 * blockIdx.z);
  const int c = bid & 7, i = bid >> 3;          // c: XCD, i: 0..95
  const int cx = c & 1, cy = c >> 1;
  const int xl = i & 3, rest = i >> 2;
  const int yl = rest & 7, zw = rest >> 3;      // zw: 0..2
  const int m0 = (cy * 8 + yl) * 128;
  const int n0 = (cx * 4 + xl) * 128;
  if (zw == 2) {
    gemm_body<2>(x, wvt, (void*)Vt, &lA[0][0], &lB[0][0], m0, n0);
  } else {
    gemm_body<0>(x, (zw == 0) ? wqt : wkt, (zw == 0) ? (void*)Q : (void*)K,
                 &lA[0][0], &lB[0][0], m0, n0);
  }
}

// ---------- out GEMM fused with combine: A = (O0+O1)*inv on the fly ---------
// 64x128 tile, dbuf, reg-staged A-combine, operand-swapped -> float4 stores.
// XCD (gx=1, gy=8): XCD c owns y = 8k+c.
__global__ __launch_bounds__(256) void out_kernel(const u16* __restrict__ Opart,
    const float* __restrict__ Lpart, const u16* __restrict__ wot,
    float* __restrict__ out) {
  __shared__ __attribute__((aligned(16))) u16 lA[2][64*32];
  __shared__ __attribute__((aligned(16))) u16 lB[2][128*32];
  const int t = threadIdx.x;
  const int lane = t & 63, w = t >> 6;
  const int wm = w >> 1, wn = w & 1;
  const int q4 = lane >> 4, l15 = lane & 15;
  const int bid = blockIdx.x + 8 * blockIdx.y;
  const int c = bid & 7, i = bid >> 3;          // i: 0..63
  const int m0 = ((i >> 3) * 8 + c) * 64;
  const int n0 = (i & 7) * 128;

  // A: 256 chunks (1/thread, reg-staged+combined); B: 512 chunks (2/thread)
  const int rA = t >> 2, gA = (t & 3) ^ (rA & 3);
  const int tokA = m0 + rA;
  const int bA = tokA >> 11, nA = tokA & (N_TOK-1);
  const int lbase = bA*NHEAD*N_TOK + nA;      // + head*N_TOK (+32*N_TOK for half1)
  const size_t oBase = (size_t)tokA*D_MODEL + gA*8;

  const int c0 = t, c1 = 256 + t;
  const int r0 = c0 >> 2, g0 = (c0 & 3) ^ (r0 & 3);
  const int r1 = c1 >> 2, g1 = (c1 & 3) ^ (r1 & 3);

  f32x4 acc[2][4] = {};

  // prologue: stage A(0) via reg-combine, B(0) via global_load_lds
  {
    uint4 o0 = *(const uint4*)(Opart + oBase);
    uint4 o1 = *(const uint4*)(Opart + (size_t)(M_TOT*D_MODEL) + oBase);
    float l0 = Lpart[lbase];                 // head(it=0) = 0
    float l1 = Lpart[32*N_TOK + lbase];
    float inv = 1.0f / (l0 + l1);
    uint4 res;
    res.x = comb2(o0.x, o1.x, inv); res.y = comb2(o0.y, o1.y, inv);
    res.z = comb2(o0.z, o1.z, inv); res.w = comb2(o0.w, o1.w, inv);
    *(uint4*)(&lA[0][t*8]) = res;
  }
  gl2lds16(wot + (size_t)(n0 + r0)*D_MODEL + g0*8, &lB[0][c0*8]);
  gl2lds16(wot + (size_t)(n0 + r1)*D_MODEL + g1*8, &lB[0][c1*8]);

  for (int it = 0; it < 32; ++it) {
    const int cur = it & 1;
    __syncthreads();
    uint4 o0, o1; float l0 = 0.f, l1 = 0.f;
    if (it + 1 < 32) {
      const int kn = (it + 1) * 32;
      o0 = *(const uint4*)(Opart + oBase + kn);
      o1 = *(const uint4*)(Opart + (size_t)(M_TOT*D_MODEL) + oBase + kn);
      const int head = (it + 1) >> 1;
      l0 = Lpart[head*N_TOK + lbase];
      l1 = Lpart[32*N_TOK + head*N_TOK + lbase];
      u16* dB = &lB[cur ^ 1][0];
      gl2lds16(wot + (size_t)(n0 + r0)*D_MODEL + kn + g0*8, dB + c0*8);
      gl2lds16(wot + (size_t)(n0 + r1)*D_MODEL + kn + g1*8, dB + c1*8);
    }
    const u16* sA = &lA[cur][0]; const u16* sB = &lB[cur][0];
    bf16x8 af[2], bfr[4];
#pragma unroll
    for (int mi = 0; mi < 2; ++mi) {
      int r = wm*32 + mi*16 + l15;
      af[mi] = *(const bf16x8*)(sA + r*32 + ((q4 ^ (r & 3)) * 8));
    }
#pragma unroll
    for (int ni = 0; ni < 4; ++ni) {
      int r = wn*64 + ni*16 + l15;
      bfr[ni] = *(const bf16x8*)(sB + r*32 + ((q4 ^ (r & 3)) * 8));
    }
#pragma unroll
    for (int mi = 0; mi < 2; ++mi)
#pragma unroll
      for (int ni = 0; ni < 4; ++ni)
        acc[mi][ni] = __builtin_amdgcn_mfma_f32_16x16x32_bf16(bfr[ni], af[mi], acc[mi][ni], 0, 0, 0);
    if (it + 1 < 32) {
      float inv = 1.0f / (l0 + l1);
      uint4 res;
      res.x = comb2(o0.x, o1.x, inv); res.y = comb2(o0.y, o1.y, inv);
      res.z = comb2(o0.z, o1.z, inv); res.w = comb2(o0.w, o1.w, inv);
      *(uint4*)(&lA[cur ^ 1][t*8]) = res;
    }
  }

  // swapped epilogue: acc regs run along output cols -> float4 stores
#pragma unroll
  for (int mi = 0; mi < 2; ++mi) {
#pragma unroll
    for (int ni = 0; ni < 4; ++ni) {
      const int tok  = m0 + wm*32 + mi*16 + l15;
      const int col0 = n0 + wn*64 + ni*16 + q4*4;
      *(f32x4*)(out + (size_t)tok*D_MODEL + col0) = acc[mi][ni];
    }
  }
}

// ---------- flash attention, S^T form, kv-split x2, double-buffered kv-64 ---
// r9 structure (best measured). P in registers (permlane16_swap), lsum via
// ones-MFMA, QK C-zero hoisted. XCD partition: XCD c owns bh = {c,c+8,c+16,
// c+24} -> K/V per XCD = 2MB, fully L2-resident. FETCH 41 -> 12.3MB.
__global__ __launch_bounds__(256, 4) void attn_kernel(const u16* __restrict__ Qg,
    const u16* __restrict__ Kg, const u16* __restrict__ Vtg,
    u16* __restrict__ Opart, float* __restrict__ Lpart) {
  __shared__ __attribute__((aligned(16))) u16 lds[16384];
  const int t = threadIdx.x;
  const int lane = t & 63, w = t >> 6;
  const int q4 = lane >> 4, l15 = lane & 15;
  const int q4sw = ((q4 & 1) << 1) | (q4 >> 1);   // k<->kv row permutation
  const int bid = blockIdx.x + 32 * blockIdx.y;
  const int c = bid & 7, i = bid >> 3;            // i: 0..127
  const int bh = (i & 3) * 8 + c;
  const int xw = i >> 2;                          // 0..31
  const int qb = xw >> 1, half = xw & 1;
  const int qw0 = qb * 128 + w * 32;
  const size_t kvBase = (size_t)bh * (N_TOK * HDIM);

  const int ck0 = t, ck1 = 256 + t;
  const int kr0 = ck0 >> 3, kg0 = (ck0 & 7) ^ (kr0 & 7);
  const int kr1 = ck1 >> 3, kg1 = (ck1 & 7) ^ (kr1 & 7);

  bf16x8 qf[2][2];
#pragma unroll
  for (int ni = 0; ni < 2; ++ni)
#pragma unroll
    for (int kk = 0; kk < 2; ++kk)
      qf[ni][kk] = *(const bf16x8*)(Qg + kvBase +
                    (size_t)(qw0 + ni*16 + l15)*HDIM + kk*32 + q4*8);

  f32x4 accO[4][2] = {};
  f32x4 accL[2] = {};                       // lsum accumulators (all-rows equal)
  const f32x4 fzero = {0.f, 0.f, 0.f, 0.f}; // hoisted zero C-operand for QK
  union { unsigned uu[4]; bf16x8 v; } onesU;
  onesU.uu[0] = 0x3F803F80u; onesU.uu[1] = 0x3F803F80u;
  onesU.uu[2] = 0x3F803F80u; onesU.uu[3] = 0x3F803F80u;
  const bf16x8 ones = onesU.v;              // bf16 1.0 x8

  const int kvStart = half * 1024;
  gl2lds16(Kg  + kvBase + (size_t)(kvStart + kr0)*HDIM + kg0*8, lds + ck0*8);
  gl2lds16(Kg  + kvBase + (size_t)(kvStart + kr1)*HDIM + kg1*8, lds + ck1*8);
  gl2lds16(Vtg + kvBase + (size_t)kr0*N_TOK + kvStart + kg0*8,  lds + 8192 + ck0*8);
  gl2lds16(Vtg + kvBase + (size_t)kr1*N_TOK + kvStart + kg1*8,  lds + 8192 + ck1*8);

  for (int it = 0; it < 16; ++it) {
    const int cur = it & 1;
    __syncthreads();
    if (it + 1 < 16) {
      const int kvn = kvStart + (it + 1) * 64;
      u16* dK = lds + (cur ^ 1) * 4096;
      u16* dV = lds + 8192 + (cur ^ 1) * 4096;
      gl2lds16(Kg  + kvBase + (size_t)(kvn + kr0)*HDIM + kg0*8, dK + ck0*8);
      gl2lds16(Kg  + kvBase + (size_t)(kvn + kr1)*HDIM + kg1*8, dK + ck1*8);
      gl2lds16(Vtg + kvBase + (size_t)kr0*N_TOK + kvn + kg0*8,  dV + ck0*8);
      gl2lds16(Vtg + kvBase + (size_t)kr1*N_TOK + kvn + kg1*8,  dV + ck1*8);
    }
    const u16* sK = lds + cur * 4096;
    const u16* sV = lds + 8192 + cur * 4096;

    // ---- QK^T + exp2, P packed to bf16 words in registers ----
    unsigned wv[4][2][2];   // [mip][ni][j] : all indices compile-time after unroll
#pragma unroll
    for (int mip = 0; mip < 4; ++mip) {
      const int kv = mip*16 + l15;
      __builtin_amdgcn_s_setprio(1);
      bf16x8 a0 = *(const bf16x8*)(sK + kv*64 + (((q4    ) ^ (l15 & 7)) * 8));
      bf16x8 a1 = *(const bf16x8*)(sK + kv*64 + (((4 + q4) ^ (l15 & 7)) * 8));
      f32x4 s0, s1;
      s0 = __builtin_amdgcn_mfma_f32_16x16x32_bf16(a0, qf[0][0], fzero, 0, 0, 0);
      s1 = __builtin_amdgcn_mfma_f32_16x16x32_bf16(a0, qf[1][0], fzero, 0, 0, 0);
      s0 = __builtin_amdgcn_mfma_f32_16x16x32_bf16(a1, qf[0][1], s0, 0, 0, 0);
      s1 = __builtin_amdgcn_mfma_f32_16x16x32_bf16(a1, qf[1][1], s1, 0, 0, 0);
      __builtin_amdgcn_s_setprio(0);
      wv[mip][0][0] = pk2bf(__builtin_amdgcn_exp2f(s0[0]), __builtin_amdgcn_exp2f(s0[1]));
      wv[mip][0][1] = pk2bf(__builtin_amdgcn_exp2f(s0[2]), __builtin_amdgcn_exp2f(s0[3]));
      wv[mip][1][0] = pk2bf(__builtin_amdgcn_exp2f(s1[0]), __builtin_amdgcn_exp2f(s1[1]));
      wv[mip][1][1] = pk2bf(__builtin_amdgcn_exp2f(s1[2]), __builtin_amdgcn_exp2f(s1[3]));
    }

    // ---- permlane16_swap: rows (q4 groups) -> PV B-fragments, no LDS ----
    // After swap(x=w(m0,j), y=w(m1,j)): x' = [x.r0, y.r0, x.r2, y.r2],
    //                                   y' = [x.r1, y.r1, x.r3, y.r3].
    // Lane row q4 then holds kv {0-7 | 16-23 | 8-15 | 24-31} (+32*kk2),
    // i.e. kv-group swap(q4) — matched by q4sw on the V read below.
    bf16x8 bp[2][2];
#pragma unroll
    for (int ni = 0; ni < 2; ++ni)
#pragma unroll
      for (int kk2 = 0; kk2 < 2; ++kk2) {
        unsigned x0 = wv[2*kk2][ni][0], x1 = wv[2*kk2][ni][1];
        unsigned y0 = wv[2*kk2+1][ni][0], y1 = wv[2*kk2+1][ni][1];
        asm("v_permlane16_swap_b32 %0, %1" : "+v"(x0), "+v"(y0));
        asm("v_permlane16_swap_b32 %0, %1" : "+v"(x1), "+v"(y1));
        union { unsigned u[4]; bf16x8 v; } pb;
        pb.u[0] = x0; pb.u[1] = x1; pb.u[2] = y0; pb.u[3] = y1;
        bp[ni][kk2] = pb.v;
      }

    // ---- PV (+ lsum via ones-MFMA) ----
    __builtin_amdgcn_s_setprio(1);
#pragma unroll
    for (int kk2 = 0; kk2 < 2; ++kk2) {
      accL[0] = __builtin_amdgcn_mfma_f32_16x16x32_bf16(ones, bp[0][kk2], accL[0], 0, 0, 0);
      accL[1] = __builtin_amdgcn_mfma_f32_16x16x32_bf16(ones, bp[1][kk2], accL[1], 0, 0, 0);
#pragma unroll
      for (int mi2 = 0; mi2 < 4; ++mi2) {
        const int d = mi2*16 + l15;
        bf16x8 av = *(const bf16x8*)(sV + d*64 + (((kk2*4 + q4sw) ^ (d & 7)) * 8));
#pragma unroll
        for (int ni = 0; ni < 2; ++ni)
          accO[mi2][ni] = __builtin_amdgcn_mfma_f32_16x16x32_bf16(av, bp[ni][kk2], accO[mi2][ni], 0, 0, 0);
      }
    }
    __builtin_amdgcn_s_setprio(0);
  }

  // epilogue: bf16 partial O^T (unnormalized) + fp32 partial row-sums.
  // accL[ni][r] holds sum_kv P[kv][q] for q=qw0+ni*16+l15 in EVERY lane/reg.
  const int b = bh >> 4, head = bh & (NHEAD-1);
  u16* Obase = Opart + (size_t)half * (M_TOT * D_MODEL);
#pragma unroll
  for (int ni = 0; ni < 2; ++ni) {
    const int q = qw0 + ni*16 + l15;
    if (q4 == 0)
      Lpart[(size_t)half*(32*N_TOK) + bh*N_TOK + q] = accL[ni][0];
    const size_t rb = ((size_t)(b*N_TOK + q))*D_MODEL + head*HDIM + q4*4;
#pragma unroll
    for (int mi2 = 0; mi2 < 4; ++mi2) {
      uint2 u;
      u.x = pk2bf(accO[mi2][ni][0], accO[mi2][ni][1]);
      u.y = pk2bf(accO[mi2][ni][2], accO[mi2][ni][3]);
      *(uint2*)(Obase + rb + mi2*16) = u;
    }
  }
}

extern "C" void kernel_launch(void* const* d_in, const int* in_sizes, int n_in,
                              void* d_out, int out_size, void* d_ws, size_t ws_size,
                              hipStream_t stream) {
  const float* x  = (const float*)d_in[0];
  const float* Wq = (const float*)d_in[1];
  const float* Wk = (const float*)d_in[2];
  const float* Wv = (const float*)d_in[3];
  const float* Wo = (const float*)d_in[4];
  float* out = (float*)d_out;

  char* ws = (char*)d_ws;
  u16* wqt  = (u16*)(ws + (8u  << 20));       // 2 MB each, transposed [out][k]
  u16* wkt  = (u16*)(ws + (10u << 20));
  u16* wvt  = (u16*)(ws + (12u << 20));
  u16* wot  = (u16*)(ws + (14u << 20));
  u16* Qw   = (u16*)(ws + (16u << 20));       // 8 MB  [bh][n][64]  (pre-scaled)
  u16* Kw   = (u16*)(ws + (24u << 20));       // 8 MB  [bh][n][64]
  u16* Vtw  = (u16*)(ws + (32u << 20));       // 8 MB  [bh][64][n]
  u16* Op   = (u16*)(ws + (48u << 20));       // 16 MB [2][4096][1024] bf16
  float* Lp = (float*)(ws + (64u << 20));     // 512KB [2][32][2048] fp32
  (void)in_sizes; (void)n_in; (void)out_size; (void)ws_size;

  prep_kernel<<<dim3(32, 32, 4), dim3(32, 8), 0, stream>>>(Wq, Wk, Wv, Wo,
                                                           wqt, wkt, wvt, wot);
  qkv_kernel<<<dim3(8, 32, 3), 256, 0, stream>>>(x, wqt, wkt, wvt, Qw, Kw, Vtw);
  attn_kernel<<<dim3(32, 32), 256, 0, stream>>>(Qw, Kw, Vtw, Op, Lp);
  out_kernel<<<dim3(8, 64), 256, 0, stream>>>(Op, Lp, wot, out);
}